// Round 15
// baseline (54.589 us; speedup 1.0000x reference)
//
#include <hip/hip_runtime.h>

#define C_IN     7
#define D_MODEL  512
#define TAO      3
#define M_TAPS   5
#define KERNELS  73            // D_MODEL / C_IN
#define B_SZ     32
#define L_SZ     4096
#define TB       64            // t-positions per block
#define NTB      (L_SZ / TB)   // 64
#define ROWS     (TB + 17)     // 81 staged rows
#define SHIFT    3             // xs row r at index r+3 -> chunk fills 16B-aligned
#define RPAD     88
#define CHUNK    8             // rows per chunk
#define NCH      (TB / CHUNK)  // 8
#define NT       576           // 8 compute waves + 1 store wave

// Non-drained barrier (LDS ordering only; global stores stay in flight).
#define LDS_BARRIER()                                          \
    do {                                                       \
        __builtin_amdgcn_sched_barrier(0);                     \
        asm volatile("s_waitcnt lgkmcnt(0)" ::: "memory");     \
        __builtin_amdgcn_sched_barrier(0);                     \
        __builtin_amdgcn_s_barrier();                          \
        __builtin_amdgcn_sched_barrier(0);                     \
    } while (0)

__global__ __launch_bounds__(NT, 4) void trc_conv_kernel(
    const float* __restrict__ x,          // [B, L, C_IN]
    const float* __restrict__ conv_w,     // [73, 6, 3]
    const float* __restrict__ conv_b,     // [73]
    const float* __restrict__ leftout_w,  // [1, 6, 3]
    const float* __restrict__ leftout_b,  // [1]
    float* __restrict__ out)              // [B, L, 512]
{
    __shared__ float xs[C_IN][RPAD];
    __shared__ __align__(16) float buf[2][CHUNK][D_MODEL];   // 32 KB dbuf out-tile

    const int tid = threadIdx.x;
    const int wv  = tid >> 6;        // 0..7 compute, 8 store specialist
    const int ln  = tid & 63;
    const int b   = blockIdx.x / NTB;
    const int tb  = blockIdx.x % NTB;
    const int t0  = tb * TB;

    // Stage x rows [t0-16, t0+TB] (circular), transposed [ch][row], +3 shift.
    // ROWS*C_IN = 567 <= 576: single pass.
    const float* xb = x + (size_t)b * L_SZ * C_IN;
    if (tid < ROWS * C_IN) {
        int r = tid / C_IN, c = tid - r * C_IN;
        int g = t0 - 16 + r;
        if (g < 0)      g += L_SZ;
        if (g >= L_SZ)  g -= L_SZ;
        xs[c][r + SHIFT] = xb[(size_t)g * C_IN + c];
    }
    __syncthreads();

    if (wv < 8) {
        // ---------------- COMPUTE WAVES (d = tid, 0..511) ----------------
        const int d = tid;
        int ch;
        const float* wsrc;
        float bias;
        if (d < C_IN * KERNELS) {
            ch = d / KERNELS;
            int o = d - ch * KERNELS;
            wsrc = conv_w + o * 18;
            bias = conv_b[o];
        } else {
            ch = C_IN - 1;
            wsrc = leftout_w;
            bias = leftout_b[0];
        }
        const float* __restrict__ rowp = &xs[ch][SHIFT];

        float wreg[18];
        #pragma unroll
        for (int j = 0; j < 18; ++j) {
            int k = j % 3;
            int m = (15 + k - j) / 3;
            wreg[j] = wsrc[m * 3 + k];
        }

        const bool first = (tb == 0), last = (tb == NTB - 1);

        auto edge_eval = [&](int tl) -> float {
            float acc = bias;
            #pragma unroll
            for (int k = 0; k < 3; ++k) {
                int tt = t0 + tl + k - 1;
                if (tt < 0)      tt += L_SZ;
                if (tt >= L_SZ)  tt -= L_SZ;
                if (tt >= M_TAPS * TAO) {
                    int lt = tl + 15 + k;
                    #pragma unroll
                    for (int m = 0; m < 6; ++m)
                        acc = fmaf(rowp[lt - 3 * m], wreg[15 + k - 3 * m], acc);
                }
            }
            return acc;
        };

        float win[25];
        #pragma unroll
        for (int q = 0; q < 17; ++q) win[q] = rowp[q];

        for (int c = 0; c < NCH; ++c) {
            float* __restrict__ bc = &buf[c & 1][0][0];

            // Fill rows 8c+17..8c+24: lds idx 8c+20 -> 16B aligned, 2x b128.
            {
                float4 f0 = *(const float4*)&rowp[8 * c + 17];
                float4 f1 = *(const float4*)&rowp[8 * c + 21];
                win[17] = f0.x; win[18] = f0.y; win[19] = f0.z; win[20] = f0.w;
                win[21] = f1.x; win[22] = f1.y; win[23] = f1.z; win[24] = f1.w;
            }

            #pragma unroll
            for (int i = 0; i < CHUNK; ++i) {
                float acc = bias;
                #pragma unroll
                for (int j = 0; j < 18; ++j)
                    acc = fmaf(win[i + j], wreg[j], acc);
                bc[i * D_MODEL + d] = acc;       // stride-1 across lanes
            }
            #pragma unroll
            for (int q = 0; q < 17; ++q) win[q] = win[q + 8];

            // Cold edge fix-ups (block-uniform; 2/64 blocks).
            if (first && c < 2) {
                for (int i = 0; i < CHUNK; ++i)
                    bc[i * D_MODEL + d] = edge_eval(c * CHUNK + i);
            }
            if (last && c == NCH - 1) {
                bc[(CHUNK - 1) * D_MODEL + d] = edge_eval(TB - 1);
            }

            LDS_BARRIER();   // publish chunk c; store wave reads it next iter
        }
    } else {
        // ---------------- STORE WAVE (wv == 8) ----------------
        // Consumes chunk c-1 while compute fills chunk c. Pure read+store
        // stream, no vmcnt drain: back-to-back dwordx4, block-sequential.
        float4* o4 = (float4*)(out + ((size_t)b * L_SZ + t0) * D_MODEL);

        for (int c = 0; c < NCH; ++c) {
            if (c > 0) {
                const float4* bv = (const float4*)&buf[(c - 1) & 1][0][0];
                float4 v[8];
                #pragma unroll
                for (int g = 0; g < 8; ++g) v[g] = bv[g * 64 + ln];
                #pragma unroll
                for (int g = 0; g < 8; ++g)
                    o4[(size_t)(c - 1) * 1024 + g * 64 + ln] = v[g];
                #pragma unroll
                for (int g = 0; g < 8; ++g) v[g] = bv[(g + 8) * 64 + ln];
                #pragma unroll
                for (int g = 0; g < 8; ++g)
                    o4[(size_t)(c - 1) * 1024 + (g + 8) * 64 + ln] = v[g];
            }
            LDS_BARRIER();
        }
        // Final chunk (no barrier needed; other waves have exited or will).
        {
            const float4* bv = (const float4*)&buf[(NCH - 1) & 1][0][0];
            float4 v[8];
            #pragma unroll
            for (int g = 0; g < 8; ++g) v[g] = bv[g * 64 + ln];
            #pragma unroll
            for (int g = 0; g < 8; ++g)
                o4[(size_t)(NCH - 1) * 1024 + g * 64 + ln] = v[g];
            #pragma unroll
            for (int g = 0; g < 8; ++g) v[g] = bv[(g + 8) * 64 + ln];
            #pragma unroll
            for (int g = 0; g < 8; ++g)
                o4[(size_t)(NCH - 1) * 1024 + (g + 8) * 64 + ln] = v[g];
        }
    }
}

extern "C" void kernel_launch(void* const* d_in, const int* in_sizes, int n_in,
                              void* d_out, int out_size, void* d_ws, size_t ws_size,
                              hipStream_t stream) {
    const float* x          = (const float*)d_in[0];
    const float* conv_w     = (const float*)d_in[1];
    const float* conv_b     = (const float*)d_in[2];
    const float* leftout_w  = (const float*)d_in[3];
    const float* leftout_b  = (const float*)d_in[4];
    float* out = (float*)d_out;

    dim3 grid(B_SZ * NTB);   // 2048 blocks x 576 threads
    trc_conv_kernel<<<grid, NT, 0, stream>>>(x, conv_w, conv_b,
                                             leftout_w, leftout_b, out);
}

// Round 16
// 49.557 us; speedup vs baseline: 1.1016x; 1.1016x over previous
//
#include <hip/hip_runtime.h>

#define C_IN     7
#define D_MODEL  512
#define TAO      3
#define M_TAPS   5
#define KERNELS  73            // D_MODEL / C_IN
#define B_SZ     32
#define L_SZ     4096
#define TB       64            // t-positions per block
#define NTB      (L_SZ / TB)   // 64
#define ROWS     (TB + 17)     // 81 staged rows
#define SHIFT    3             // xs row r at index r+3 -> chunk fills 16B-aligned
#define RPAD     88
#define CHUNK    8             // rows per wave-local chunk
#define NCH      (TB / CHUNK)  // 8

__global__ __launch_bounds__(512, 5) void trc_conv_kernel(
    const float* __restrict__ x,          // [B, L, C_IN]
    const float* __restrict__ conv_w,     // [73, 6, 3]
    const float* __restrict__ conv_b,     // [73]
    const float* __restrict__ leftout_w,  // [1, 6, 3]
    const float* __restrict__ leftout_b,  // [1]
    float* __restrict__ out)              // [B, L, 512]
{
    __shared__ float xs[C_IN][RPAD];
    __shared__ __align__(16) float buf[8][2][CHUNK][64];  // per-wave dbuf out-tiles (32 KB)

    const int tid = threadIdx.x;
    const int wv  = tid >> 6;        // wave id 0..7 -> owns cols [64*wv, 64*wv+64)
    const int ln  = tid & 63;
    const int b   = blockIdx.x / NTB;
    const int tb  = blockIdx.x % NTB;
    const int t0  = tb * TB;

    // Stage x rows [t0-16, t0+TB] (circular), transposed [ch][row], +3 shift.
    const float* xb = x + (size_t)b * L_SZ * C_IN;
    for (int i = tid; i < ROWS * C_IN; i += 512) {
        int r = i / C_IN, c = i - r * C_IN;
        int g = t0 - 16 + r;
        if (g < 0)      g += L_SZ;
        if (g >= L_SZ)  g -= L_SZ;
        xs[c][r + SHIFT] = xb[(size_t)g * C_IN + c];
    }
    __syncthreads();   // the ONLY barrier

    // Column ownership: d = 64*wv + ln (== tid).
    const int d = tid;
    int ch;
    const float* wsrc;
    float bias;
    if (d < C_IN * KERNELS) {
        ch = d / KERNELS;
        int o = d - ch * KERNELS;
        wsrc = conv_w + o * 18;
        bias = conv_b[o];
    } else {
        ch = C_IN - 1;
        wsrc = leftout_w;
        bias = leftout_b[0];
    }
    const float* __restrict__ rowp = &xs[ch][SHIFT];   // rowp[r] = x row t0-16+r

    // FIR weights by row-offset j (0 = oldest = row t-16): k=j%3, m=(15+k-j)/3.
    float wreg[18];
    #pragma unroll
    for (int j = 0; j < 18; ++j) {
        int k = j % 3;
        int m = (15 + k - j) / 3;
        wreg[j] = wsrc[m * 3 + k];
    }

    const bool first = (tb == 0), last = (tb == NTB - 1);

    // Masked edge-row evaluation (wrap + validity).
    auto edge_eval = [&](int tl) -> float {
        float acc = bias;
        #pragma unroll
        for (int k = 0; k < 3; ++k) {
            int tt = t0 + tl + k - 1;
            if (tt < 0)      tt += L_SZ;
            if (tt >= L_SZ)  tt -= L_SZ;
            if (tt >= M_TAPS * TAO) {
                int lt = tl + 15 + k;
                #pragma unroll
                for (int m = 0; m < 6; ++m)
                    acc = fmaf(rowp[lt - 3 * m], wreg[15 + k - 3 * m], acc);
            }
        }
        return acc;
    };

    float* __restrict__ bufw = &buf[wv][0][0][0];        // wave-private
    const int lr = ln >> 4, lc = ln & 15;                // store lane mapping
    float4* base4 = (float4*)(out + ((size_t)b * L_SZ + t0) * D_MODEL + wv * 64);

    // Sliding window (static indices), chunk = 8 rows, b128 fills.
    float win[25];
    #pragma unroll
    for (int q = 0; q < 17; ++q) win[q] = rowp[q];

    // Parity store registers: eA holds even-chunk readback, eB odd-chunk.
    // A register is overwritten 2 chunks after its store issues -> the
    // compiler's vmcnt WAR wait targets a long-retired store (no stall).
    float4 eA0, eA1, eB0, eB1;

    for (int u = 0; u < NCH / 2; ++u) {
        const int c0 = 2 * u, c1 = 2 * u + 1;

        // ---------------- even chunk c0 (slot 0) ----------------
        {
            float4 f0 = *(const float4*)&rowp[8 * c0 + 17];
            float4 f1 = *(const float4*)&rowp[8 * c0 + 21];
            win[17] = f0.x; win[18] = f0.y; win[19] = f0.z; win[20] = f0.w;
            win[21] = f1.x; win[22] = f1.y; win[23] = f1.z; win[24] = f1.w;

            float* __restrict__ bc = bufw;               // slot 0
            #pragma unroll
            for (int i = 0; i < CHUNK; ++i) {
                float acc = bias;
                #pragma unroll
                for (int j = 0; j < 18; ++j)
                    acc = fmaf(win[i + j], wreg[j], acc);
                bc[i * 64 + ln] = acc;                   // stride-1: conflict-free
            }
            #pragma unroll
            for (int q = 0; q < 17; ++q) win[q] = win[q + 8];

            if (first && c0 < 2) {                       // chunk 0 only
                for (int i = 0; i < CHUNK; ++i)
                    bc[i * 64 + ln] = edge_eval(c0 * CHUNK + i);
            }

            const float4* bv = (const float4*)bufw;
            float4 n0 = bv[ln];
            float4 n1 = bv[ln + 64];
            __builtin_amdgcn_sched_barrier(0);

            if (u > 0) {                                 // store odd chunk c0-1
                base4[(size_t)((c0 - 1) * CHUNK + 0 + lr) * (D_MODEL / 4) + lc] = eB0;
                base4[(size_t)((c0 - 1) * CHUNK + 4 + lr) * (D_MODEL / 4) + lc] = eB1;
            }
            eA0 = n0; eA1 = n1;
        }

        // ---------------- odd chunk c1 (slot 1) ----------------
        {
            float4 f0 = *(const float4*)&rowp[8 * c1 + 17];
            float4 f1 = *(const float4*)&rowp[8 * c1 + 21];
            win[17] = f0.x; win[18] = f0.y; win[19] = f0.z; win[20] = f0.w;
            win[21] = f1.x; win[22] = f1.y; win[23] = f1.z; win[24] = f1.w;

            float* __restrict__ bc = bufw + CHUNK * 64;  // slot 1
            #pragma unroll
            for (int i = 0; i < CHUNK; ++i) {
                float acc = bias;
                #pragma unroll
                for (int j = 0; j < 18; ++j)
                    acc = fmaf(win[i + j], wreg[j], acc);
                bc[i * 64 + ln] = acc;
            }
            #pragma unroll
            for (int q = 0; q < 17; ++q) win[q] = win[q + 8];

            if (first && c1 < 2) {                       // chunk 1 only
                for (int i = 0; i < CHUNK; ++i)
                    bc[i * 64 + ln] = edge_eval(c1 * CHUNK + i);
            }
            if (last && c1 == NCH - 1) {
                bc[(CHUNK - 1) * 64 + ln] = edge_eval(TB - 1);
            }

            const float4* bv = (const float4*)(bufw + CHUNK * 64);
            float4 n0 = bv[ln];
            float4 n1 = bv[ln + 64];
            __builtin_amdgcn_sched_barrier(0);

            // store even chunk c1-1 = c0
            base4[(size_t)(c0 * CHUNK + 0 + lr) * (D_MODEL / 4) + lc] = eA0;
            base4[(size_t)(c0 * CHUNK + 4 + lr) * (D_MODEL / 4) + lc] = eA1;

            eB0 = n0; eB1 = n1;
        }
    }
    // Epilogue: last odd chunk.
    base4[(size_t)((NCH - 1) * CHUNK + 0 + lr) * (D_MODEL / 4) + lc] = eB0;
    base4[(size_t)((NCH - 1) * CHUNK + 4 + lr) * (D_MODEL / 4) + lc] = eB1;
}

extern "C" void kernel_launch(void* const* d_in, const int* in_sizes, int n_in,
                              void* d_out, int out_size, void* d_ws, size_t ws_size,
                              hipStream_t stream) {
    const float* x          = (const float*)d_in[0];
    const float* conv_w     = (const float*)d_in[1];
    const float* conv_b     = (const float*)d_in[2];
    const float* leftout_w  = (const float*)d_in[3];
    const float* leftout_b  = (const float*)d_in[4];
    float* out = (float*)d_out;

    dim3 grid(B_SZ * NTB);   // 2048 blocks x 512 threads
    trc_conv_kernel<<<grid, 512, 0, stream>>>(x, conv_w, conv_b,
                                              leftout_w, leftout_b, out);
}